// Round 9
// baseline (274.068 us; speedup 1.0000x reference)
//
#include <hip/hip_runtime.h>

// Problem constants (from reference)
#define C_IN   8
#define HH     32
#define WW     32
#define C_OUT  32
#define KK     4
#define SS     2
#define PP     1
#define HO     16
#define WO     16
#define IN_FEAT  8192   // C_IN*HH*WW
#define OUT_FEAT 8192   // C_OUT*HO*WO

typedef float f32x4 __attribute__((ext_vector_type(4)));

// ---------------------------------------------------------------------------
// R9 theory: our portion (~100us) is invariant across fused-branchy (R6),
// hand fill+scatter (R7) and driver memset+scatter (R8) -- even the driver's
// 6.6 TB/s fill kernel takes ~90us for our 268 MB instead of 41us. The extra
// is HBM traffic, not instruction shape: the harness poison fill (inside the
// timed region) leaves L3 (256 MiB) full of DIRTY poison lines; our write-
// allocate stream evicts one per line allocated -> ~268 MB poison writeback
// + 268 MB payload = 536 MB ~= 81us + overhead. `nt` (R6) was neutral
// because on CDNA nt is an evict-priority hint -- it still allocates.
//
// Fix attempt: system-scope bypass stores. gfx950 store flags `sc0 sc1`
// (cdna4_isa.md: the gfx940+ cache-scope spellings) write through to the
// memory-visible point without allocating in L2/L3 -> no poison evictions
// inside our kernel. No HIP builtin exists -> inline asm. Fused structure:
// every wmat byte written exactly once by full-line bypass stores (no
// partial-line bypass, no mixed cached/bypass kernels).
//
// Layout: row = c_out*256 + ho*16 + wo ; col = ci*1024 + h*32 + w
// nonzero iff h = 2*ho-1+kh, w = 2*wo-1+kw, kh,kw in [0,4), h,w in [0,32);
// value = weight[c_out, ci, kh, kw].
// ---------------------------------------------------------------------------

__device__ __forceinline__ void store_bypass(f32x4 v, f32x4* p) {
    // system-scope write-through: no L2/L3 allocation, no victim eviction
    asm volatile("global_store_dwordx4 %0, %1, off sc0 sc1 nt"
                 :: "v"(p), "v"(v));
}

__global__ __launch_bounds__(256) void fused_row_kernel(const float* __restrict__ bounds,
                                                        const float* __restrict__ weight,
                                                        const float* __restrict__ bias,
                                                        float* __restrict__ wmat,
                                                        float* __restrict__ out_bounds,
                                                        float* __restrict__ bias_bs) {
    const int gid  = blockIdx.x * 256 + threadIdx.x;
    const int row  = gid >> 6;                 // 0..8191 (wave-uniform)
    const int lane = threadIdx.x & 63;

    const int c_out = row >> 8;
    const int ho    = (row >> 4) & 15;
    const int wo    = row & 15;
    const int hs    = ho * SS - PP;            // window h start (may be -1)
    const int ws    = wo * SS - PP;            // window w start (may be -1)

    // per-lane constants for the stream loop
    const int  lh   = lane >> 3;               // h offset within an 8-row block
    const int  w0   = (lane & 7) * 4;          // f32x4 w base (0..28)
    const int  kwb  = w0 - ws;                 // kw of element j is kwb+j
    const bool whit = (kwb >= -3) & (kwb <= 3);

    // wave-uniform h-block hit mask (forced scalar)
    unsigned hbmask = 0;
    {
        const int loh = hs > 0 ? hs : 0;
        const int hih = (hs + 3) < 31 ? (hs + 3) : 31;
#pragma unroll
        for (int hb = 0; hb < 4; ++hb)
            if (hb * 8 <= hih && loh <= hb * 8 + 7) hbmask |= 1u << hb;
    }
    hbmask = __builtin_amdgcn_readfirstlane(hbmask);

    const f32x4 zero4 = (f32x4){0.f, 0.f, 0.f, 0.f};
    f32x4* __restrict__ rp = reinterpret_cast<f32x4*>(wmat + (size_t)row * IN_FEAT) + lane;
    const float* __restrict__ wco = weight + c_out * (C_IN * KK * KK);

    // ---- stream the 32 KB row via bypass stores ----
    for (int ci = 0; ci < C_IN; ++ci) {
#pragma unroll
        for (int hb = 0; hb < 4; ++hb, rp += 64) {
            if (hbmask & (1u << hb)) {         // s_cbranch: skip on miss blocks
                f32x4 v = zero4;
                const int kh = hb * 8 + lh - hs;
                if (((unsigned)kh < (unsigned)KK) & whit) {
                    const float* wb = wco + ci * (KK * KK) + kh * KK;
#pragma unroll
                    for (int j = 0; j < 4; ++j) {
                        const int kw = kwb + j;
                        if ((unsigned)kw < (unsigned)KK) v[j] = wb[kw];
                    }
                }
                store_bypass(v, rp);
            } else {
                store_bypass(zero4, rp);       // fill-kernel shaped common path
            }
        }
    }

    // ---- bounds + bias (2 taps per lane over the 128-tap stencil) ----
    const float* lptr = bounds;                // bounds[0]
    const float* uptr = bounds + IN_FEAT;      // bounds[1]
    float lo = 0.f, up = 0.f;
#pragma unroll
    for (int s = 0; s < 2; ++s) {
        const int t  = lane + 64 * s;          // tap 0..127
        const int ci = t >> 4;
        const int kh = (t >> 2) & 3;
        const int kw = t & 3;
        const int h  = hs + kh;
        const int w  = ws + kw;
        if ((unsigned)h < (unsigned)HH && (unsigned)w < (unsigned)WW) {
            const float wv  = wco[ci * (KK * KK) + kh * KK + kw];
            const int   col = ci * (HH * WW) + h * WW + w;
            const float lv = lptr[col];
            const float uv = uptr[col];
            const float wp = fmaxf(wv, 0.f);
            const float wm = fminf(wv, 0.f);
            lo = fmaf(wp, lv, fmaf(wm, uv, lo));
            up = fmaf(wp, uv, fmaf(wm, lv, up));
        }
    }
#pragma unroll
    for (int off = 32; off; off >>= 1) {
        lo += __shfl_down(lo, off, 64);
        up += __shfl_down(up, off, 64);
    }
    if (lane == 0) {
        const float b = bias[c_out];
        out_bounds[row]            = lo + b;   // lower  [32,16,16]
        out_bounds[OUT_FEAT + row] = up + b;   // upper
        bias_bs[row] = b;                      // repeat_interleave(bias, 256)
    }
}

extern "C" void kernel_launch(void* const* d_in, const int* in_sizes, int n_in,
                              void* d_out, int out_size, void* d_ws, size_t ws_size,
                              hipStream_t stream) {
    const float* bounds = (const float*)d_in[0];   // [2,8,32,32]
    const float* weight = (const float*)d_in[1];   // [32,8,4,4]
    const float* bias   = (const float*)d_in[2];   // [32]
    // d_in[3] = assignment (unused by forward)

    float* out     = (float*)d_out;
    float* wmat    = out + 2 * OUT_FEAT;                      // after out_bounds (16384)
    float* bias_bs = out + 2 * OUT_FEAT + (size_t)OUT_FEAT * IN_FEAT;

    // 8192 rows x 1 wave = 524288 threads -> 2048 blocks of 256
    fused_row_kernel<<<2048, 256, 0, stream>>>(bounds, weight, bias, wmat, out, bias_bs);
}

// Round 10
// 260.262 us; speedup vs baseline: 1.0530x; 1.0530x over previous
//
#include <hip/hip_runtime.h>

// Problem constants (from reference)
#define C_IN   8
#define HH     32
#define WW     32
#define C_OUT  32
#define KK     4
#define SS     2
#define PP     1
#define HO     16
#define WO     16
#define IN_FEAT  8192   // C_IN*HH*WW
#define OUT_FEAT 8192   // C_OUT*HO*WO

// ---------------------------------------------------------------------------
// FINAL (revert-to-best): fused single-kernel Toeplitz row stream + bounds.
// Session findings (R6-R9): five structural variants -- plain fused (259.7),
// nt fused (260.8), hand fill+scatter (273.5), driver hipMemsetAsync+scatter
// (262.6), sc0sc1nt bypass fused (274.1) -- are flat within fill-tail noise.
// The timed region is dominated by a fixed 1.074 GB harness poison fill
// (~162us @ 6.6 TB/s); our 268 MB output write (~98us) is drain-coupled to
// the poison stream through the memory-side 256 MiB Infinity Cache, floor
// ~85us. Store flavor (cached/nt/sc0sc1) and even the driver's own 6.6 TB/s
// fill kernel cannot beat it -> the residual is environmental, not
// kernel-addressable. Keeping the simplest best-measured variant.
//
// One wave per Toeplitz row (8192 rows, 64 lanes); 32 x 1KB coalesced f32x4
// stores per row. Wave-uniform h-block hit mask via readfirstlane -> miss
// path is fill-kernel shaped (store zero, advance). Bounds (back-substitution
// == forward interval conv; tighten is identity) from 2 taps/lane + wave
// shuffle-reduce, overlapping the store drain.
//
// Layout: row = c_out*256 + ho*16 + wo ; col = ci*1024 + h*32 + w
// nonzero iff h = 2*ho-1+kh, w = 2*wo-1+kw, kh,kw in [0,4), h,w in [0,32);
// value = weight[c_out, ci, kh, kw].
// ---------------------------------------------------------------------------
__global__ __launch_bounds__(256) void fused_row_kernel(const float* __restrict__ bounds,
                                                        const float* __restrict__ weight,
                                                        const float* __restrict__ bias,
                                                        float* __restrict__ wmat,
                                                        float* __restrict__ out_bounds,
                                                        float* __restrict__ bias_bs) {
    const int gid  = blockIdx.x * 256 + threadIdx.x;
    const int row  = gid >> 6;                 // 0..8191 (wave-uniform)
    const int lane = threadIdx.x & 63;

    const int c_out = row >> 8;
    const int ho    = (row >> 4) & 15;
    const int wo    = row & 15;
    const int hs    = ho * SS - PP;            // window h start (may be -1)
    const int ws    = wo * SS - PP;            // window w start (may be -1)

    // per-lane constants for the stream loop
    const int  lh   = lane >> 3;               // h offset within an 8-row block
    const int  w0   = (lane & 7) * 4;          // float4 w base (0..28)
    const int  kwb  = w0 - ws;                 // kw of element j is kwb+j
    const bool whit = (kwb >= -3) & (kwb <= 3);

    // wave-uniform h-block hit mask (forced scalar)
    unsigned hbmask = 0;
    {
        const int loh = hs > 0 ? hs : 0;
        const int hih = (hs + 3) < 31 ? (hs + 3) : 31;
#pragma unroll
        for (int hb = 0; hb < 4; ++hb)
            if (hb * 8 <= hih && loh <= hb * 8 + 7) hbmask |= 1u << hb;
    }
    hbmask = __builtin_amdgcn_readfirstlane(hbmask);

    const float4 zero4 = make_float4(0.f, 0.f, 0.f, 0.f);
    float4* __restrict__ rp = reinterpret_cast<float4*>(wmat + (size_t)row * IN_FEAT) + lane;
    const float* __restrict__ wco = weight + c_out * (C_IN * KK * KK);

    // ---- stream the 32 KB row ----
    for (int ci = 0; ci < C_IN; ++ci) {
#pragma unroll
        for (int hb = 0; hb < 4; ++hb, rp += 64) {
            if (hbmask & (1u << hb)) {         // s_cbranch: skip on miss blocks
                float4 v = zero4;
                const int kh = hb * 8 + lh - hs;
                if (((unsigned)kh < (unsigned)KK) & whit) {
                    const float* wb = wco + ci * (KK * KK) + kh * KK;
                    float* vp = &v.x;
#pragma unroll
                    for (int j = 0; j < 4; ++j) {
                        const int kw = kwb + j;
                        if ((unsigned)kw < (unsigned)KK) vp[j] = wb[kw];
                    }
                }
                *rp = v;
            } else {
                *rp = zero4;                   // fill-kernel shaped common path
            }
        }
    }

    // ---- bounds + bias (2 taps per lane over the 128-tap stencil) ----
    const float* lptr = bounds;                // bounds[0]
    const float* uptr = bounds + IN_FEAT;      // bounds[1]
    float lo = 0.f, up = 0.f;
#pragma unroll
    for (int s = 0; s < 2; ++s) {
        const int t  = lane + 64 * s;          // tap 0..127
        const int ci = t >> 4;
        const int kh = (t >> 2) & 3;
        const int kw = t & 3;
        const int h  = hs + kh;
        const int w  = ws + kw;
        if ((unsigned)h < (unsigned)HH && (unsigned)w < (unsigned)WW) {
            const float wv  = wco[ci * (KK * KK) + kh * KK + kw];
            const int   col = ci * (HH * WW) + h * WW + w;
            const float lv = lptr[col];
            const float uv = uptr[col];
            const float wp = fmaxf(wv, 0.f);
            const float wm = fminf(wv, 0.f);
            lo = fmaf(wp, lv, fmaf(wm, uv, lo));
            up = fmaf(wp, uv, fmaf(wm, lv, up));
        }
    }
#pragma unroll
    for (int off = 32; off; off >>= 1) {
        lo += __shfl_down(lo, off, 64);
        up += __shfl_down(up, off, 64);
    }
    if (lane == 0) {
        const float b = bias[c_out];
        out_bounds[row]            = lo + b;   // lower  [32,16,16]
        out_bounds[OUT_FEAT + row] = up + b;   // upper
        bias_bs[row] = b;                      // repeat_interleave(bias, 256)
    }
}

extern "C" void kernel_launch(void* const* d_in, const int* in_sizes, int n_in,
                              void* d_out, int out_size, void* d_ws, size_t ws_size,
                              hipStream_t stream) {
    const float* bounds = (const float*)d_in[0];   // [2,8,32,32]
    const float* weight = (const float*)d_in[1];   // [32,8,4,4]
    const float* bias   = (const float*)d_in[2];   // [32]
    // d_in[3] = assignment (unused by forward)

    float* out     = (float*)d_out;
    float* wmat    = out + 2 * OUT_FEAT;                      // after out_bounds (16384)
    float* bias_bs = out + 2 * OUT_FEAT + (size_t)OUT_FEAT * IN_FEAT;

    // 8192 rows x 1 wave = 524288 threads -> 2048 blocks of 256
    fused_row_kernel<<<2048, 256, 0, stream>>>(bounds, weight, bias, wmat, out, bias_bs);
}